// Round 1
// baseline (361.951 us; speedup 1.0000x reference)
//
#include <hip/hip_runtime.h>
#include <math.h>

// SS2D (VMamba v2) forward — MI355X gfx950, fp32 throughout.
//
// Pipeline (9 dispatches on `stream`):
//  k_transpose : W_in -> WtIn (96x384), W_out -> WtOut (192x96)  [coalesced GEMM reads]
//  k_inproj    : xz = x @ W_in^T ; xin = xz[:,:192], z = silu(xz[:,192:])
//  k_conv      : depthwise 3x3 SAME + bias + silu -> xc  (layout (p, d) channels-last)
//  k_xdbl      : per (b,k,l): 38 dots of len 192 -> dtr(6), Bm(16), Cm(16)
//  k_delta     : delta[b,k,l,d] = softplus(dtr @ dtw[k,d,:] + bias)
//  k_scan1/2/3 : chunked linear-recurrence scan (16 chunks of 64) -> yout (b,k,l,d)
//  k_out       : merge + LayerNorm(192) + gate(z) + out GEMM (96x192)

#define DMODEL 96
#define DINNER 192
#define NSTATE 16
#define RANK 6
#define KDIR 4
#define BATCH 4
#define HH 64
#define WW2 64
#define NPIX (BATCH * HH * WW2)       // 16384
#define LP 1024                       // (H/2)*(W/2)
#define NCH 16                        // scan chunks
#define CHUNK 64                      // LP / NCH
#define NBK (BATCH * KDIR)            // 16
#define NSTATES (NBK * DINNER * NSTATE) // 49152

__device__ __forceinline__ float silu_f(float x) {
    return x / (1.0f + __expf(-x));
}

// (k, l) -> h*64+w within one batch image.
// Scan order: k0: l=hs*32+ws -> (2hs,2ws); k1: l=ws*32+hs -> (2hs+1,2ws);
//             k2: l=hs*32+ws -> (2hs,2ws+1); k3: l=ws*32+hs -> (2hs+1,2ws+1)
__device__ __forceinline__ int pix_of(int k, int l) {
    int i = l >> 5, j = l & 31;
    int h, w;
    if (k == 0)      { h = 2 * i;     w = 2 * j;     }
    else if (k == 1) { h = 2 * j + 1; w = 2 * i;     }
    else if (k == 2) { h = 2 * i;     w = 2 * j + 1; }
    else             { h = 2 * j + 1; w = 2 * i + 1; }
    return h * 64 + w;
}

__global__ __launch_bounds__(256) void k_transpose(
        const float* __restrict__ W_in, const float* __restrict__ W_out,
        float* __restrict__ WtIn, float* __restrict__ WtOut) {
    int i = blockIdx.x * 256 + threadIdx.x;
    if (i < 96 * 384) {               // WtIn[c*384+e] = W_in[e*96+c]
        int c = i / 384, e = i % 384;
        WtIn[i] = W_in[e * 96 + c];
    }
    if (i < 192 * 96) {               // WtOut[d*96+o] = W_out[o*192+d]
        int d = i / 96, o = i % 96;
        WtOut[i] = W_out[o * 192 + d];
    }
}

// 32 pixels per block, 256 threads: thread (pi=t>>6, ei=t&63) computes
// acc[j in 0..5][pp in 0..7] = xz[p0+pi*8+pp][j*64+ei]
__global__ __launch_bounds__(256) void k_inproj(
        const float* __restrict__ x, const float* __restrict__ WtIn,
        float* __restrict__ xin, float* __restrict__ z) {
    __shared__ float xs[32 * 96];
    int p0 = blockIdx.x * 32;
    int t = threadIdx.x;
    for (int i = t; i < 32 * 96; i += 256) xs[i] = x[p0 * 96 + i];
    __syncthreads();
    int ei = t & 63;
    int pi = t >> 6;
    float acc[6][8];
    #pragma unroll
    for (int j = 0; j < 6; ++j)
        #pragma unroll
        for (int pp = 0; pp < 8; ++pp) acc[j][pp] = 0.0f;
    for (int c = 0; c < 96; ++c) {
        float wv[6];
        #pragma unroll
        for (int j = 0; j < 6; ++j) wv[j] = WtIn[c * 384 + j * 64 + ei];
        #pragma unroll
        for (int pp = 0; pp < 8; ++pp) {
            float xv = xs[(pi * 8 + pp) * 96 + c];
            #pragma unroll
            for (int j = 0; j < 6; ++j) acc[j][pp] = fmaf(wv[j], xv, acc[j][pp]);
        }
    }
    #pragma unroll
    for (int j = 0; j < 6; ++j) {
        int e = j * 64 + ei;
        #pragma unroll
        for (int pp = 0; pp < 8; ++pp) {
            int p = p0 + pi * 8 + pp;
            if (e < 192) xin[p * 192 + e] = acc[j][pp];
            else         z[p * 192 + (e - 192)] = silu_f(acc[j][pp]);
        }
    }
}

__global__ __launch_bounds__(192) void k_conv(
        const float* __restrict__ xin, const float* __restrict__ cw,
        const float* __restrict__ cb, float* __restrict__ xc) {
    int p = blockIdx.x;
    int d = threadIdx.x;
    int b = p >> 12;
    int hw = p & 4095;
    int h = hw >> 6, w = hw & 63;
    float acc = cb[d];
    #pragma unroll
    for (int i = 0; i < 3; ++i) {
        int hh = h + i - 1;
        if ((unsigned)hh >= 64u) continue;
        #pragma unroll
        for (int j = 0; j < 3; ++j) {
            int ww = w + j - 1;
            if ((unsigned)ww >= 64u) continue;
            acc = fmaf(xin[(b * 4096 + hh * 64 + ww) * 192 + d],
                       cw[d * 9 + i * 3 + j], acc);
        }
    }
    xc[p * 192 + d] = silu_f(acc);
}

__global__ __launch_bounds__(256) void k_xdbl(
        const float* __restrict__ xc, const float* __restrict__ xpw,
        float* __restrict__ dtr, float* __restrict__ Bm, float* __restrict__ Cm) {
    int idx = blockIdx.x * 256 + threadIdx.x;
    if (idx >= NBK * LP * 38) return;
    int c = idx % 38;
    int bkl = idx / 38;
    int l = bkl & 1023;
    int bk = bkl >> 10;
    int b = bk >> 2, k = bk & 3;
    const float4* xr = (const float4*)(xc + (b * 4096 + pix_of(k, l)) * 192);
    const float4* wr = (const float4*)(xpw + (k * 38 + c) * 192);
    float acc = 0.0f;
    #pragma unroll 4
    for (int q = 0; q < 48; ++q) {
        float4 a = xr[q], wv = wr[q];
        acc += a.x * wv.x + a.y * wv.y + a.z * wv.z + a.w * wv.w;
    }
    if (c < 6)       dtr[bkl * 6 + c] = acc;
    else if (c < 22) Bm[bkl * 16 + (c - 6)] = acc;
    else             Cm[bkl * 16 + (c - 22)] = acc;
}

__global__ __launch_bounds__(192) void k_delta(
        const float* __restrict__ dtr, const float* __restrict__ dtw,
        const float* __restrict__ dtb, float* __restrict__ delta) {
    int bkl = blockIdx.x;
    int d = threadIdx.x;
    int k = (bkl >> 10) & 3;
    const float* r = dtr + bkl * 6;
    const float* wp = dtw + (k * 192 + d) * 6;
    float acc = dtb[k * 192 + d];
    #pragma unroll
    for (int q = 0; q < 6; ++q) acc = fmaf(wp[q], r[q], acc);
    float sp = (acc > 20.0f) ? acc : log1pf(__expf(acc));
    delta[bkl * 192 + d] = sp;
}

// Pass 1: per chunk, compute P = prod(dA), q = h after chunk with h_in = 0.
__global__ __launch_bounds__(192) void k_scan1(
        const float* __restrict__ delta, const float* __restrict__ xc,
        const float* __restrict__ Bm, const float* __restrict__ A_logs,
        float* __restrict__ Pbuf, float* __restrict__ Qbuf) {
    __shared__ float sB[CHUNK * 16];
    int bk = blockIdx.x / NCH;
    int ch = blockIdx.x % NCH;
    int b = bk >> 2, k = bk & 3;
    int d = threadIdx.x;
    float A[16];
    #pragma unroll
    for (int n = 0; n < 16; ++n) A[n] = -__expf(A_logs[(k * 192 + d) * 16 + n]);
    for (int i = d; i < CHUNK * 16; i += 192)
        sB[i] = Bm[(bk * 1024 + ch * CHUNK) * 16 + i];
    __syncthreads();
    float h[16], P[16];
    #pragma unroll
    for (int n = 0; n < 16; ++n) { h[n] = 0.0f; P[n] = 1.0f; }
    int lbase = bk * 1024 + ch * CHUNK;
    for (int l = 0; l < CHUNK; ++l) {
        float dlt = delta[(lbase + l) * 192 + d];
        float u = xc[(b * 4096 + pix_of(k, ch * CHUNK + l)) * 192 + d];
        float du = dlt * u;
        const float* Bl = sB + l * 16;
        #pragma unroll
        for (int n = 0; n < 16; ++n) {
            float e = __expf(dlt * A[n]);
            h[n] = fmaf(e, h[n], du * Bl[n]);
            P[n] *= e;
        }
    }
    int base = (ch * NBK + bk) * DINNER * 16 + d * 16;
    #pragma unroll
    for (int n = 0; n < 16; ++n) { Pbuf[base + n] = P[n]; Qbuf[base + n] = h[n]; }
}

// Pass 2: prefix over chunks; Hst[c] = h at start of chunk c.
__global__ __launch_bounds__(256) void k_scan2(
        const float* __restrict__ Pbuf, const float* __restrict__ Qbuf,
        float* __restrict__ Hst) {
    int s = blockIdx.x * 256 + threadIdx.x;
    if (s >= NSTATES) return;
    float h = 0.0f;
    for (int c = 0; c < NCH; ++c) {
        Hst[c * NSTATES + s] = h;
        h = fmaf(Pbuf[c * NSTATES + s], h, Qbuf[c * NSTATES + s]);
    }
}

// Pass 3: replay with correct h_in, emit y = sum_n h*C + u*D.
__global__ __launch_bounds__(192) void k_scan3(
        const float* __restrict__ delta, const float* __restrict__ xc,
        const float* __restrict__ Bm, const float* __restrict__ Cm,
        const float* __restrict__ A_logs, const float* __restrict__ Ds,
        const float* __restrict__ Hst, float* __restrict__ yout) {
    __shared__ float sB[CHUNK * 16];
    __shared__ float sC[CHUNK * 16];
    int bk = blockIdx.x / NCH;
    int ch = blockIdx.x % NCH;
    int b = bk >> 2, k = bk & 3;
    int d = threadIdx.x;
    float A[16];
    #pragma unroll
    for (int n = 0; n < 16; ++n) A[n] = -__expf(A_logs[(k * 192 + d) * 16 + n]);
    float Dp = Ds[k * 192 + d];
    for (int i = d; i < CHUNK * 16; i += 192) {
        sB[i] = Bm[(bk * 1024 + ch * CHUNK) * 16 + i];
        sC[i] = Cm[(bk * 1024 + ch * CHUNK) * 16 + i];
    }
    __syncthreads();
    float h[16];
    int base = (ch * NBK + bk) * DINNER * 16 + d * 16;
    #pragma unroll
    for (int n = 0; n < 16; ++n) h[n] = Hst[base + n];
    int lbase = bk * 1024 + ch * CHUNK;
    for (int l = 0; l < CHUNK; ++l) {
        float dlt = delta[(lbase + l) * 192 + d];
        float u = xc[(b * 4096 + pix_of(k, ch * CHUNK + l)) * 192 + d];
        float du = dlt * u;
        const float* Bl = sB + l * 16;
        const float* Cl = sC + l * 16;
        float y = 0.0f;
        #pragma unroll
        for (int n = 0; n < 16; ++n) {
            float e = __expf(dlt * A[n]);
            h[n] = fmaf(e, h[n], du * Bl[n]);
            y = fmaf(h[n], Cl[n], y);
        }
        yout[(lbase + l) * 192 + d] = fmaf(u, Dp, y);
    }
}

// merge + LayerNorm(192) + gate + out GEMM (96 outs of len-192 dots)
__global__ __launch_bounds__(192) void k_out(
        const float* __restrict__ yout, const float* __restrict__ z,
        const float* __restrict__ lng, const float* __restrict__ lnb,
        const float* __restrict__ WoT, float* __restrict__ out) {
    __shared__ float sg[192];
    __shared__ float red[8];
    int p = blockIdx.x;
    int d = threadIdx.x;
    int b = p >> 12;
    int hw = p & 4095;
    int h = hw >> 6, w = hw & 63;
    int i2 = h >> 1, j2 = w >> 1;
    int k, l;
    if (((h & 1) == 0) && ((w & 1) == 0)) { k = 0; l = i2 * 32 + j2; }
    else if (((h & 1) == 1) && ((w & 1) == 0)) { k = 1; l = j2 * 32 + i2; }
    else if ((h & 1) == 0) { k = 2; l = i2 * 32 + j2; }
    else { k = 3; l = j2 * 32 + i2; }
    int bk = b * 4 + k;
    float yv = yout[(bk * 1024 + l) * 192 + d];
    float s = yv, s2 = yv * yv;
    #pragma unroll
    for (int off = 32; off > 0; off >>= 1) {
        s  += __shfl_down(s, off, 64);
        s2 += __shfl_down(s2, off, 64);
    }
    int wid = d >> 6;
    if ((d & 63) == 0) { red[wid] = s; red[wid + 4] = s2; }
    __syncthreads();
    float ts = red[0] + red[1] + red[2];
    float ts2 = red[4] + red[5] + red[6];
    float mu = ts * (1.0f / 192.0f);
    float var = ts2 * (1.0f / 192.0f) - mu * mu;
    float rstd = rsqrtf(var + 1e-5f);
    float g = ((yv - mu) * rstd * lng[d] + lnb[d]) * z[p * 192 + d];
    sg[d] = g;
    __syncthreads();
    if (d < 96) {
        float acc = 0.0f;
        #pragma unroll 4
        for (int dd = 0; dd < 192; ++dd)
            acc = fmaf(sg[dd], WoT[dd * 96 + d], acc);
        out[p * 96 + d] = acc;
    }
}

extern "C" void kernel_launch(void* const* d_in, const int* in_sizes, int n_in,
                              void* d_out, int out_size, void* d_ws, size_t ws_size,
                              hipStream_t stream) {
    const float* x    = (const float*)d_in[0];
    const float* W_in = (const float*)d_in[1];
    const float* cw   = (const float*)d_in[2];
    const float* cb   = (const float*)d_in[3];
    const float* xpw  = (const float*)d_in[4];
    const float* dtw  = (const float*)d_in[5];
    const float* dtb  = (const float*)d_in[6];
    const float* Alog = (const float*)d_in[7];
    const float* Ds   = (const float*)d_in[8];
    const float* lng  = (const float*)d_in[9];
    const float* lnb  = (const float*)d_in[10];
    const float* Wout = (const float*)d_in[11];
    float* out = (float*)d_out;

    float* ws = (float*)d_ws;
    size_t off = 0;
    float* WtIn  = ws + off; off += 96 * 384;
    float* WtOut = ws + off; off += 192 * 96;
    float* xin   = ws + off; off += (size_t)NPIX * 192;   // also reused as `delta`
    float* zbuf  = ws + off; off += (size_t)NPIX * 192;
    float* xc    = ws + off; off += (size_t)NPIX * 192;
    float* dtr   = ws + off; off += (size_t)NBK * LP * 6;
    float* Bm    = ws + off; off += (size_t)NBK * LP * 16;
    float* Cm    = ws + off; off += (size_t)NBK * LP * 16;
    float* Pbuf  = ws + off; off += (size_t)NCH * NSTATES;
    float* Qbuf  = ws + off; off += (size_t)NCH * NSTATES;
    float* Hst   = ws + off; off += (size_t)NCH * NSTATES;
    float* yout  = ws + off; off += (size_t)NBK * LP * 192;
    float* delta = xin;  // xin fully consumed by k_conv before k_delta writes

    hipLaunchKernelGGL(k_transpose, dim3(144), dim3(256), 0, stream,
                       W_in, Wout, WtIn, WtOut);
    hipLaunchKernelGGL(k_inproj, dim3(NPIX / 32), dim3(256), 0, stream,
                       x, WtIn, xin, zbuf);
    hipLaunchKernelGGL(k_conv, dim3(NPIX), dim3(192), 0, stream,
                       xin, cw, cb, xc);
    hipLaunchKernelGGL(k_xdbl, dim3((NBK * LP * 38 + 255) / 256), dim3(256), 0, stream,
                       xc, xpw, dtr, Bm, Cm);
    hipLaunchKernelGGL(k_delta, dim3(NBK * LP), dim3(192), 0, stream,
                       dtr, dtw, dtb, delta);
    hipLaunchKernelGGL(k_scan1, dim3(NBK * NCH), dim3(192), 0, stream,
                       delta, xc, Bm, Alog, Pbuf, Qbuf);
    hipLaunchKernelGGL(k_scan2, dim3(NSTATES / 256), dim3(256), 0, stream,
                       Pbuf, Qbuf, Hst);
    hipLaunchKernelGGL(k_scan3, dim3(NBK * NCH), dim3(192), 0, stream,
                       delta, xc, Bm, Cm, Alog, Ds, Hst, yout);
    hipLaunchKernelGGL(k_out, dim3(NPIX), dim3(192), 0, stream,
                       yout, zbuf, lng, lnb, WtOut, out);
}

// Round 2
// 232.450 us; speedup vs baseline: 1.5571x; 1.5571x over previous
//
#include <hip/hip_runtime.h>
#include <math.h>

// SS2D (VMamba v2) forward — MI355X gfx950, fp32 throughout.
//
// Pipeline (9 dispatches):
//  k_transpose : W_in -> WtIn (96x384), W_out -> WtOut (192x96)
//  k_inproj    : xz = x @ W_in^T ; xin = xz[:,:192], z = silu(xz[:,192:])
//  k_conv      : depthwise 3x3 SAME + bias + silu -> xg in SCAN ORDER (bk,l,d)
//  k_xdbl      : LDS-tiled GEMM per (bk, 64-l tile): 38x192 @ 192x64 -> dtr/Bm/Cm
//  k_scan1/2/3 : chunked linear-recurrence scan (32 chunks of 32), delta inline
//  k_ln        : merge + LayerNorm(192) + gate(z) -> g (pixel order)
//  k_oproj     : out = g @ W_out^T, 32-pixel tiles, g staged in LDS

#define DINNER 192
#define NSTATE 16
#define KDIR 4
#define BATCH 4
#define NPIX (BATCH * 64 * 64)          // 16384
#define LP 1024
#define NCH 32                          // scan chunks
#define CHUNK 32                        // LP / NCH
#define NBK (BATCH * KDIR)              // 16
#define NSTATES (NBK * DINNER * NSTATE) // 49152

__device__ __forceinline__ float silu_f(float x) {
    return x / (1.0f + __expf(-x));
}

__global__ __launch_bounds__(256) void k_transpose(
        const float* __restrict__ W_in, const float* __restrict__ W_out,
        float* __restrict__ WtIn, float* __restrict__ WtOut) {
    int i = blockIdx.x * 256 + threadIdx.x;
    if (i < 96 * 384) {               // WtIn[c*384+e] = W_in[e*96+c]
        int c = i / 384, e = i % 384;
        WtIn[i] = W_in[e * 96 + c];
    }
    if (i < 192 * 96) {               // WtOut[d*96+o] = W_out[o*192+d]
        int d = i / 96, o = i % 96;
        WtOut[i] = W_out[o * 192 + d];
    }
}

// 32 pixels/block; thread (pi=t>>6, ei=t&63) -> acc over 6 e-groups x 8 pixels
__global__ __launch_bounds__(256) void k_inproj(
        const float* __restrict__ x, const float* __restrict__ WtIn,
        float* __restrict__ xin, float* __restrict__ z) {
    __shared__ float xs[32 * 96];
    int p0 = blockIdx.x * 32;
    int t = threadIdx.x;
    for (int i = t; i < 32 * 96; i += 256) xs[i] = x[p0 * 96 + i];
    __syncthreads();
    int ei = t & 63;
    int pi = t >> 6;
    float acc[6][8];
    #pragma unroll
    for (int j = 0; j < 6; ++j)
        #pragma unroll
        for (int pp = 0; pp < 8; ++pp) acc[j][pp] = 0.0f;
    for (int c = 0; c < 96; ++c) {
        float wv[6];
        #pragma unroll
        for (int j = 0; j < 6; ++j) wv[j] = WtIn[c * 384 + j * 64 + ei];
        #pragma unroll
        for (int pp = 0; pp < 8; ++pp) {
            float xv = xs[(pi * 8 + pp) * 96 + c];
            #pragma unroll
            for (int j = 0; j < 6; ++j) acc[j][pp] = fmaf(wv[j], xv, acc[j][pp]);
        }
    }
    #pragma unroll
    for (int j = 0; j < 6; ++j) {
        int e = j * 64 + ei;
        #pragma unroll
        for (int pp = 0; pp < 8; ++pp) {
            int p = p0 + pi * 8 + pp;
            if (e < 192) xin[p * 192 + e] = acc[j][pp];
            else         z[p * 192 + (e - 192)] = silu_f(acc[j][pp]);
        }
    }
}

// depthwise conv; OUTPUT written in scan order xg[(bk*1024+l)*192+d]
__global__ __launch_bounds__(192) void k_conv(
        const float* __restrict__ xin, const float* __restrict__ cw,
        const float* __restrict__ cb, float* __restrict__ xg) {
    int p = blockIdx.x;
    int d = threadIdx.x;
    int b = p >> 12;
    int hw = p & 4095;
    int h = hw >> 6, w = hw & 63;
    float acc = cb[d];
    #pragma unroll
    for (int i = 0; i < 3; ++i) {
        int hh = h + i - 1;
        if ((unsigned)hh >= 64u) continue;
        #pragma unroll
        for (int j = 0; j < 3; ++j) {
            int ww = w + j - 1;
            if ((unsigned)ww >= 64u) continue;
            acc = fmaf(xin[(b * 4096 + hh * 64 + ww) * 192 + d],
                       cw[d * 9 + i * 3 + j], acc);
        }
    }
    int kq = (h & 1) ? ((w & 1) ? 3 : 1) : ((w & 1) ? 2 : 0);
    int l = (kq == 1 || kq == 3) ? ((w >> 1) * 32 + (h >> 1))
                                 : ((h >> 1) * 32 + (w >> 1));
    xg[((size_t)(b * 4 + kq) * 1024 + l) * 192 + d] = silu_f(acc);
}

// GEMM 38x192 @ 192x64 per block. W in LDS (broadcast), X in LDS (stride 194).
__global__ __launch_bounds__(256) void k_xdbl(
        const float* __restrict__ xg, const float* __restrict__ xpw,
        float* __restrict__ dtr, float* __restrict__ Bm, float* __restrict__ Cm) {
    __shared__ float sW[40 * 192];     // rows 38,39 zero
    __shared__ float sX[64 * 194];
    int bk = blockIdx.x >> 4;
    int tile = blockIdx.x & 15;
    int k = bk & 3;
    int t = threadIdx.x;
    const float4* wsrc = (const float4*)(xpw + k * 38 * 192);
    for (int i = t; i < 40 * 48; i += 256) {
        float4 v = make_float4(0.f, 0.f, 0.f, 0.f);
        if (i < 38 * 48) v = wsrc[i];
        ((float4*)sW)[i] = v;
    }
    const float2* xsrc = (const float2*)(xg + (size_t)(bk * 1024 + tile * 64) * 192);
    for (int i = t; i < 64 * 96; i += 256) {
        int f = i * 2;
        int row = f / 192, col = f - row * 192;
        *(float2*)&sX[row * 194 + col] = xsrc[i];
    }
    __syncthreads();
    int l = t & 63, w = t >> 6;
    int cbase = w * 10;
    float acc[10];
    #pragma unroll
    for (int i = 0; i < 10; ++i) acc[i] = 0.0f;
    #pragma unroll 4
    for (int q = 0; q < 96; ++q) {
        float2 xv = *(const float2*)&sX[l * 194 + 2 * q];
        #pragma unroll
        for (int ci = 0; ci < 10; ++ci) {
            float2 wv = *(const float2*)&sW[(cbase + ci) * 192 + 2 * q];
            acc[ci] = fmaf(xv.x, wv.x, fmaf(xv.y, wv.y, acc[ci]));
        }
    }
    int bkl = bk * 1024 + tile * 64 + l;
    #pragma unroll
    for (int ci = 0; ci < 10; ++ci) {
        int c = cbase + ci;
        if (c < 38) {
            float v = acc[ci];
            if (c < 6)       dtr[bkl * 6 + c] = v;
            else if (c < 22) Bm[bkl * 16 + (c - 6)] = v;
            else             Cm[bkl * 16 + (c - 22)] = v;
        }
    }
}

__device__ __forceinline__ float softplus_f(float a) {
    return (a > 20.0f) ? a : __logf(1.0f + __expf(a));
}

// Pass 1: per chunk, P = prod(dA), Q = h after chunk with h_in = 0. Delta inline.
__global__ __launch_bounds__(192) void k_scan1(
        const float* __restrict__ dtr, const float* __restrict__ xg,
        const float* __restrict__ Bm, const float* __restrict__ A_logs,
        const float* __restrict__ dtw, const float* __restrict__ dtb,
        float* __restrict__ Pbuf, float* __restrict__ QH) {
    __shared__ float sB[CHUNK * 16];
    int bk = blockIdx.x >> 5;
    int ch = blockIdx.x & 31;
    int k = bk & 3;
    int d = threadIdx.x;
    float A[16];
    #pragma unroll
    for (int n = 0; n < 16; ++n) A[n] = -__expf(A_logs[(k * 192 + d) * 16 + n]);
    float wp[6];
    #pragma unroll
    for (int q = 0; q < 6; ++q) wp[q] = dtw[(k * 192 + d) * 6 + q];
    float bias = dtb[k * 192 + d];
    int lbase = bk * 1024 + ch * CHUNK;
    for (int i = d; i < CHUNK * 16; i += 192) sB[i] = Bm[lbase * 16 + i];
    __syncthreads();
    float h[16], P[16];
    #pragma unroll
    for (int n = 0; n < 16; ++n) { h[n] = 0.0f; P[n] = 1.0f; }
    for (int l = 0; l < CHUNK; ++l) {
        const float* r = dtr + (size_t)(lbase + l) * 6;
        float a = bias;
        #pragma unroll
        for (int q = 0; q < 6; ++q) a = fmaf(wp[q], r[q], a);
        float dlt = softplus_f(a);
        float u = xg[(size_t)(lbase + l) * 192 + d];
        float du = dlt * u;
        const float* Bl = sB + l * 16;
        #pragma unroll
        for (int n = 0; n < 16; ++n) {
            float e = __expf(dlt * A[n]);
            h[n] = fmaf(e, h[n], du * Bl[n]);
            P[n] *= e;
        }
    }
    int base = ch * NSTATES + (bk * 16) * 192;
    #pragma unroll
    for (int n = 0; n < 16; ++n) {
        Pbuf[base + n * 192 + d] = P[n];
        QH[base + n * 192 + d] = h[n];
    }
}

// Pass 2: prefix over chunks (in place: QH becomes Hst = h at chunk start).
__global__ __launch_bounds__(256) void k_scan2(
        const float* __restrict__ Pbuf, float* QH) {
    int s = blockIdx.x * 256 + threadIdx.x;
    float h = 0.0f;
    for (int c = 0; c < NCH; ++c) {
        float q = QH[c * NSTATES + s];
        float p = Pbuf[c * NSTATES + s];
        QH[c * NSTATES + s] = h;
        h = fmaf(p, h, q);
    }
}

// Pass 3: replay with correct h_in, emit y.
__global__ __launch_bounds__(192) void k_scan3(
        const float* __restrict__ dtr, const float* __restrict__ xg,
        const float* __restrict__ Bm, const float* __restrict__ Cm,
        const float* __restrict__ A_logs, const float* __restrict__ dtw,
        const float* __restrict__ dtb, const float* __restrict__ Ds,
        const float* __restrict__ QH, float* __restrict__ yout) {
    __shared__ float sB[CHUNK * 16];
    __shared__ float sC[CHUNK * 16];
    int bk = blockIdx.x >> 5;
    int ch = blockIdx.x & 31;
    int k = bk & 3;
    int d = threadIdx.x;
    float A[16];
    #pragma unroll
    for (int n = 0; n < 16; ++n) A[n] = -__expf(A_logs[(k * 192 + d) * 16 + n]);
    float wp[6];
    #pragma unroll
    for (int q = 0; q < 6; ++q) wp[q] = dtw[(k * 192 + d) * 6 + q];
    float bias = dtb[k * 192 + d];
    float Dp = Ds[k * 192 + d];
    int lbase = bk * 1024 + ch * CHUNK;
    for (int i = d; i < CHUNK * 16; i += 192) {
        sB[i] = Bm[lbase * 16 + i];
        sC[i] = Cm[lbase * 16 + i];
    }
    __syncthreads();
    float h[16];
    int base = ch * NSTATES + (bk * 16) * 192;
    #pragma unroll
    for (int n = 0; n < 16; ++n) h[n] = QH[base + n * 192 + d];
    for (int l = 0; l < CHUNK; ++l) {
        const float* r = dtr + (size_t)(lbase + l) * 6;
        float a = bias;
        #pragma unroll
        for (int q = 0; q < 6; ++q) a = fmaf(wp[q], r[q], a);
        float dlt = softplus_f(a);
        float u = xg[(size_t)(lbase + l) * 192 + d];
        float du = dlt * u;
        const float* Bl = sB + l * 16;
        const float* Cl = sC + l * 16;
        float y = 0.0f;
        #pragma unroll
        for (int n = 0; n < 16; ++n) {
            float e = __expf(dlt * A[n]);
            h[n] = fmaf(e, h[n], du * Bl[n]);
            y = fmaf(h[n], Cl[n], y);
        }
        yout[(size_t)(lbase + l) * 192 + d] = fmaf(u, Dp, y);
    }
}

// merge + LayerNorm(192) + gate -> g (pixel order)
__global__ __launch_bounds__(192) void k_ln(
        const float* __restrict__ yout, const float* __restrict__ z,
        const float* __restrict__ lng, const float* __restrict__ lnb,
        float* __restrict__ g) {
    __shared__ float red[8];
    int p = blockIdx.x;
    int d = threadIdx.x;
    int b = p >> 12;
    int hw = p & 4095;
    int h = hw >> 6, w = hw & 63;
    int kq = (h & 1) ? ((w & 1) ? 3 : 1) : ((w & 1) ? 2 : 0);
    int l = (kq == 1 || kq == 3) ? ((w >> 1) * 32 + (h >> 1))
                                 : ((h >> 1) * 32 + (w >> 1));
    int bk = b * 4 + kq;
    float yv = yout[((size_t)bk * 1024 + l) * 192 + d];
    float s = yv, s2 = yv * yv;
    #pragma unroll
    for (int off = 32; off > 0; off >>= 1) {
        s  += __shfl_down(s, off, 64);
        s2 += __shfl_down(s2, off, 64);
    }
    int wid = d >> 6;
    if ((d & 63) == 0) { red[wid] = s; red[wid + 4] = s2; }
    __syncthreads();
    float ts = red[0] + red[1] + red[2];
    float ts2 = red[4] + red[5] + red[6];
    float mu = ts * (1.0f / 192.0f);
    float var = ts2 * (1.0f / 192.0f) - mu * mu;
    float rstd = rsqrtf(var + 1e-5f);
    g[(size_t)p * 192 + d] = ((yv - mu) * rstd * lng[d] + lnb[d]) * z[(size_t)p * 192 + d];
}

// out = g @ W_out^T ; 32 pixels/block, g tile in LDS (b128 broadcast reads)
__global__ __launch_bounds__(256) void k_oproj(
        const float* __restrict__ g, const float* __restrict__ WoT,
        float* __restrict__ out) {
    __shared__ float sg[32 * 192];
    int p0 = blockIdx.x * 32;
    int t = threadIdx.x;
    const float4* gs = (const float4*)(g + (size_t)p0 * 192);
    for (int i = t; i < 32 * 48; i += 256) ((float4*)sg)[i] = gs[i];
    __syncthreads();
    int oi = t & 31, wi = t >> 5;
    float acc[4][3];
    #pragma unroll
    for (int pp = 0; pp < 4; ++pp)
        #pragma unroll
        for (int j = 0; j < 3; ++j) acc[pp][j] = 0.0f;
    for (int dd = 0; dd < 192; dd += 4) {
        float4 q0 = *(const float4*)&sg[(wi * 4 + 0) * 192 + dd];
        float4 q1 = *(const float4*)&sg[(wi * 4 + 1) * 192 + dd];
        float4 q2 = *(const float4*)&sg[(wi * 4 + 2) * 192 + dd];
        float4 q3 = *(const float4*)&sg[(wi * 4 + 3) * 192 + dd];
        #pragma unroll
        for (int r = 0; r < 4; ++r) {
            float w0 = WoT[(dd + r) * 96 + oi];
            float w1 = WoT[(dd + r) * 96 + oi + 32];
            float w2 = WoT[(dd + r) * 96 + oi + 64];
            float e0 = (r == 0) ? q0.x : (r == 1) ? q0.y : (r == 2) ? q0.z : q0.w;
            float e1 = (r == 0) ? q1.x : (r == 1) ? q1.y : (r == 2) ? q1.z : q1.w;
            float e2 = (r == 0) ? q2.x : (r == 1) ? q2.y : (r == 2) ? q2.z : q2.w;
            float e3 = (r == 0) ? q3.x : (r == 1) ? q3.y : (r == 2) ? q3.z : q3.w;
            acc[0][0] = fmaf(e0, w0, acc[0][0]);
            acc[0][1] = fmaf(e0, w1, acc[0][1]);
            acc[0][2] = fmaf(e0, w2, acc[0][2]);
            acc[1][0] = fmaf(e1, w0, acc[1][0]);
            acc[1][1] = fmaf(e1, w1, acc[1][1]);
            acc[1][2] = fmaf(e1, w2, acc[1][2]);
            acc[2][0] = fmaf(e2, w0, acc[2][0]);
            acc[2][1] = fmaf(e2, w1, acc[2][1]);
            acc[2][2] = fmaf(e2, w2, acc[2][2]);
            acc[3][0] = fmaf(e3, w0, acc[3][0]);
            acc[3][1] = fmaf(e3, w1, acc[3][1]);
            acc[3][2] = fmaf(e3, w2, acc[3][2]);
        }
    }
    #pragma unroll
    for (int pp = 0; pp < 4; ++pp)
        #pragma unroll
        for (int j = 0; j < 3; ++j)
            out[(size_t)(p0 + wi * 4 + pp) * 96 + oi + 32 * j] = acc[pp][j];
}

extern "C" void kernel_launch(void* const* d_in, const int* in_sizes, int n_in,
                              void* d_out, int out_size, void* d_ws, size_t ws_size,
                              hipStream_t stream) {
    const float* x    = (const float*)d_in[0];
    const float* W_in = (const float*)d_in[1];
    const float* cw   = (const float*)d_in[2];
    const float* cb   = (const float*)d_in[3];
    const float* xpw  = (const float*)d_in[4];
    const float* dtw  = (const float*)d_in[5];
    const float* dtb  = (const float*)d_in[6];
    const float* Alog = (const float*)d_in[7];
    const float* Ds   = (const float*)d_in[8];
    const float* lng  = (const float*)d_in[9];
    const float* lnb  = (const float*)d_in[10];
    const float* Wout = (const float*)d_in[11];
    float* out = (float*)d_out;

    float* ws = (float*)d_ws;
    size_t off = 0;
    float* WtIn  = ws + off; off += 96 * 384;
    float* WtOut = ws + off; off += 192 * 96;
    float* xin   = ws + off; off += (size_t)NPIX * 192;   // reused as g after conv
    float* zbuf  = ws + off; off += (size_t)NPIX * 192;
    float* xg    = ws + off; off += (size_t)NPIX * 192;
    float* dtr   = ws + off; off += (size_t)NBK * LP * 6;
    float* Bm    = ws + off; off += (size_t)NBK * LP * 16;
    float* Cm    = ws + off; off += (size_t)NBK * LP * 16;
    float* yout  = ws + off; off += (size_t)NBK * LP * 192;  // Pbuf aliases 1st half
    float* QH    = ws + off; off += (size_t)NCH * NSTATES;
    float* Pbuf  = yout;   // dead before scan3 writes yout
    float* g     = xin;    // xin dead after k_conv

    hipLaunchKernelGGL(k_transpose, dim3(144), dim3(256), 0, stream,
                       W_in, Wout, WtIn, WtOut);
    hipLaunchKernelGGL(k_inproj, dim3(NPIX / 32), dim3(256), 0, stream,
                       x, WtIn, xin, zbuf);
    hipLaunchKernelGGL(k_conv, dim3(NPIX), dim3(192), 0, stream,
                       xin, cw, cb, xg);
    hipLaunchKernelGGL(k_xdbl, dim3(NBK * 16), dim3(256), 0, stream,
                       xg, xpw, dtr, Bm, Cm);
    hipLaunchKernelGGL(k_scan1, dim3(NBK * NCH), dim3(192), 0, stream,
                       dtr, xg, Bm, Alog, dtw, dtb, Pbuf, QH);
    hipLaunchKernelGGL(k_scan2, dim3(NSTATES / 256), dim3(256), 0, stream,
                       Pbuf, QH);
    hipLaunchKernelGGL(k_scan3, dim3(NBK * NCH), dim3(192), 0, stream,
                       dtr, xg, Bm, Cm, Alog, dtw, dtb, Ds, QH, yout);
    hipLaunchKernelGGL(k_ln, dim3(NPIX), dim3(192), 0, stream,
                       yout, zbuf, lng, lnb, g);
    hipLaunchKernelGGL(k_oproj, dim3(NPIX / 32), dim3(256), 0, stream,
                       g, WtOut, out);
}